// Round 3
// baseline (87.569 us; speedup 1.0000x reference)
//
#include <hip/hip_runtime.h>

// Single fused kernel. The circuit after the fused (embedding + layer-0) RYs
// is a FIXED 16x16 orthogonal map U (CNOT ring, layer-1 RYs, CNOT ring)
// depending only on qweights. z = s^T M s with M = U^T D U, and s a product
// state => z reduces to an 81-coefficient multilinear form in the per-wire
// vectors e_w = (1, cos(x_w + w0_w), sin(x_w + w0_w)):
//     z = sum_p T[p0,p1,p2,p3] * prod_w e_w[p_w]
// T[p] = (1/16) * sum_{k=0..15} (-1)^popc(k & mask1) * M[k][k ^ mask2],
// mask1 = wire-bits with p_w==1, mask2 = wire-bits with p_w==2.
//
// Round-2 lesson: a separate 1-WG precompute kernel cost ~3 us of launch +
// serialization -- more than the entire T computation. So T is now built
// REDUNDANTLY PER BLOCK in LDS (~0.25 us of concurrent in-kernel work, two
// extra barriers), deleting the second launch. Per-thread angle/sincos work
// overlaps the U/M phases (independent of T). T reads in the contraction are
// wave-uniform compile-time addresses -> LDS broadcast, conflict-free.

#define CNOT_GATE(CM, TM) { \
    _Pragma("unroll") \
    for (int idx = 0; idx < 16; ++idx) { \
        if ((idx & (CM)) && !(idx & (TM))) { \
            float tmp = st[idx]; st[idx] = st[idx | (TM)]; st[idx | (TM)] = tmp; \
        } \
    } }

#define RY_GATE(MASK, C, S) { \
    _Pragma("unroll") \
    for (int idx = 0; idx < 16; ++idx) { \
        if (!(idx & (MASK))) { \
            float u0 = st[idx], u1 = st[idx | (MASK)]; \
            st[idx]          = (C)*u0 - (S)*u1; \
            st[idx | (MASK)] = (S)*u0 + (C)*u1; \
        } \
    } }

__global__ __launch_bounds__(256) void hybrid_qnn_kernel(
    const float* __restrict__ x,
    const float* __restrict__ qw,
    const float* __restrict__ W1,
    const float* __restrict__ b1,
    const float* __restrict__ W2,
    const float* __restrict__ b2,
    float* __restrict__ out)
{
    __shared__ float U[16][16];   // U[k][col]
    __shared__ float M[16][16];
    __shared__ float Tl[81];      // multilinear tensor
    __shared__ float lz[196];     // per-block expvals
    __shared__ float lh[30];      // FC1 activations

    const int img = blockIdx.x;
    const int t   = threadIdx.x;

    // ---- per-thread embedding angles (independent of T; overlaps U/M) ----
    float C0, S0, C1, S1, C2, S2, C3, S3;
    if (t < 196) {
        const int i = t / 14;
        const int j = t - 14 * i;
        const float* xp = x + (size_t)img * 784 + i * 56 + j * 2;
        const float2 r0 = *(const float2*)xp;          // wires 0,1
        const float2 r1 = *(const float2*)(xp + 28);   // wires 2,3
        const float a0 = r0.x + qw[0];
        const float a1 = r0.y + qw[1];
        const float a2 = r1.x + qw[2];
        const float a3 = r1.y + qw[3];
        C0 = __cosf(a0); S0 = __sinf(a0);
        C1 = __cosf(a1); S1 = __sinf(a1);
        C2 = __cosf(a2); S2 = __sinf(a2);
        C3 = __cosf(a3); S3 = __sinf(a3);
    }

    // ---- U phase: 16 threads apply the fixed circuit to basis vectors ----
    if (t < 16) {
        float st[16];
        #pragma unroll
        for (int k = 0; k < 16; ++k) st[k] = (k == t) ? 1.0f : 0.0f;
        // layer-0 CNOT ring (wire q -> bit mask 8>>q)
        CNOT_GATE(8, 4); CNOT_GATE(4, 2); CNOT_GATE(2, 1); CNOT_GATE(1, 8);
        // layer-1 RYs (half angles), then CNOT ring
        float cw[4], sw[4];
        #pragma unroll
        for (int w = 0; w < 4; ++w) {
            cw[w] = __cosf(0.5f * qw[4 + w]);
            sw[w] = __sinf(0.5f * qw[4 + w]);
        }
        RY_GATE(8, cw[0], sw[0]);
        RY_GATE(4, cw[1], sw[1]);
        RY_GATE(2, cw[2], sw[2]);
        RY_GATE(1, cw[3], sw[3]);
        CNOT_GATE(8, 4); CNOT_GATE(4, 2); CNOT_GATE(2, 1); CNOT_GATE(1, 8);
        #pragma unroll
        for (int k = 0; k < 16; ++k) U[k][t] = st[k];
    }
    __syncthreads();

    // ---- M phase: M[i][j] = sum_k D_k * U[k][i] * U[k][j], D_k = +-1 ----
    {
        const int i = t >> 4, j = t & 15;
        float m = 0.f;
        #pragma unroll
        for (int k = 0; k < 16; ++k)
            m = fmaf((k < 8) ? U[k][i] : -U[k][i], U[k][j], m);
        M[i][j] = m;
    }
    __syncthreads();

    // ---- T phase: closed form over the 2^4 nonzero quadratic terms ----
    if (t < 81) {
        const int p0 = t / 27, p1 = (t / 9) % 3, p2 = (t / 3) % 3, p3 = t % 3;
        const int mask1 = ((p0 == 1) << 3) | ((p1 == 1) << 2) |
                          ((p2 == 1) << 1) |  (p3 == 1);
        const int mask2 = ((p0 == 2) << 3) | ((p1 == 2) << 2) |
                          ((p2 == 2) << 1) |  (p3 == 2);
        float acc = 0.f;
        #pragma unroll
        for (int k = 0; k < 16; ++k) {
            const float v = M[k][k ^ mask2];
            acc += (__popc(k & mask1) & 1) ? -v : v;
        }
        Tl[t] = 0.0625f * acc;
    }
    __syncthreads();

    // ---- z phase: Horner contraction over the 3x3x3x3 tensor ----
    if (t < 196) {
        const float e0[3] = {1.f, C0, S0};
        const float e1[3] = {1.f, C1, S1};
        const float e2[3] = {1.f, C2, S2};
        float z = 0.f;
        #pragma unroll
        for (int p0 = 0; p0 < 3; ++p0) {
            float s1 = 0.f;
            #pragma unroll
            for (int p1 = 0; p1 < 3; ++p1) {
                float s2 = 0.f;
                #pragma unroll
                for (int p2 = 0; p2 < 3; ++p2) {
                    const int b = ((p0 * 3 + p1) * 3 + p2) * 3;
                    float s3 = fmaf(S3, Tl[b + 2], fmaf(C3, Tl[b + 1], Tl[b]));
                    s2 = fmaf(s3, e2[p2], s2);
                }
                s1 = fmaf(s2, e1[p1], s1);
            }
            z = fmaf(s1, e0[p0], z);
        }
        lz[t] = z;
    }
    __syncthreads();

    // ---- FC1: h[o] = relu(sum_j z[j]*W1[j,o] + b1[o]); 8 segs/output ----
    if (t < 240) {
        const int o   = t >> 3;   // 0..29
        const int seg = t & 7;    // 0..7
        float acc = 0.f;
        #pragma unroll
        for (int i = 0; i < 25; ++i) {
            const int j = seg * 25 + i;
            if (j < 196) acc = fmaf(lz[j], W1[j * 30 + o], acc);
        }
        acc += __shfl_down(acc, 4, 8);
        acc += __shfl_down(acc, 2, 8);
        acc += __shfl_down(acc, 1, 8);
        if (seg == 0) lh[o] = fmaxf(acc + b1[o], 0.f);
    }
    __syncthreads();

    // ---- FC2: out = h @ W2 + b2, W2 is (30,2) row-major ----
    if (t < 2) {
        float acc = b2[t];
        #pragma unroll
        for (int k = 0; k < 30; ++k)
            acc = fmaf(lh[k], W2[k * 2 + t], acc);
        out[img * 2 + t] = acc;
    }
}

#undef CNOT_GATE
#undef RY_GATE

extern "C" void kernel_launch(void* const* d_in, const int* in_sizes, int n_in,
                              void* d_out, int out_size, void* d_ws, size_t ws_size,
                              hipStream_t stream) {
    const float* x  = (const float*)d_in[0];
    const float* qw = (const float*)d_in[1];
    const float* W1 = (const float*)d_in[2];
    const float* b1 = (const float*)d_in[3];
    const float* W2 = (const float*)d_in[4];
    const float* b2 = (const float*)d_in[5];
    float* out = (float*)d_out;

    const int B = in_sizes[0] / 784;   // 4096
    hipLaunchKernelGGL(hybrid_qnn_kernel, dim3(B), dim3(256), 0, stream,
                       x, qw, W1, b1, W2, b2, out);
}

// Round 4
// 84.042 us; speedup vs baseline: 1.0420x; 1.0420x over previous
//
#include <hip/hip_runtime.h>

// Closed-form circuit evaluation. Pulling Z0 back through the second CNOT
// ring: C2^T Z0 C2 = Z1 Z2 Z3 (layer-1 wire-0 weight drops out). Conjugating
// prod_{w=1..3}(c_w Z_w - s_w X_w) through the first CNOT ring, all
// Y-containing Pauli strings vanish on the real product state, leaving 4
// terms:
//   z =  c1c2c3 * C0*C1*C3
//      - c1c2s3 * S0*S1*C2*S3
//      - s1c2c3 * S1*S2*C3
//      - s1s2s3 * S0
// where C_w = cos(x_w + qw[w]), S_w = sin(x_w + qw[w])  (fused embedding +
// layer-0 RY), and c_w,s_w = cos/sin(qw[4+w]) for w=1,2,3 (layer-1 RYs).
// Verified against direct statevector simulation on basis / superposition
// test cases. Phase 1 is now 7 sincos + ~12 multiplies per thread; no LDS
// tensor, no extra barriers (round-3's per-block U/M/T build was a ~3 us
// regression: serial 16-lane dependent chain + 3 barriers in every block).

__global__ __launch_bounds__(256) void hybrid_qnn_kernel(
    const float* __restrict__ x,
    const float* __restrict__ qw,
    const float* __restrict__ W1,
    const float* __restrict__ b1,
    const float* __restrict__ W2,
    const float* __restrict__ b2,
    float* __restrict__ out)
{
    __shared__ float lz[196];   // per-block expvals
    __shared__ float lh[30];    // FC1 activations

    const int img = blockIdx.x;
    const int t   = threadIdx.x;

    if (t < 196) {
        const int i = t / 14;
        const int j = t - 14 * i;
        const float* xp = x + (size_t)img * 784 + i * 56 + j * 2;
        const float2 r0 = *(const float2*)xp;          // wires 0,1
        const float2 r1 = *(const float2*)(xp + 28);   // wires 2,3

        // fused embedding + layer-0 angles
        const float a0 = r0.x + qw[0];
        const float a1 = r0.y + qw[1];
        const float a2 = r1.x + qw[2];
        const float a3 = r1.y + qw[3];
        const float C0 = __cosf(a0), S0 = __sinf(a0);
        const float C1 = __cosf(a1), S1 = __sinf(a1);
        const float C2 = __cosf(a2), S2 = __sinf(a2);
        const float C3 = __cosf(a3), S3 = __sinf(a3);

        // layer-1 weight trig (wave-uniform; wire-0 weight qw[4] drops out)
        const float c1 = __cosf(qw[5]), s1 = __sinf(qw[5]);
        const float c2 = __cosf(qw[6]), s2 = __sinf(qw[6]);
        const float c3 = __cosf(qw[7]), s3 = __sinf(qw[7]);

        const float c1c2 = c1 * c2;
        float z =        (c1c2 * c3) * (C0 * C1 * C3);
        z = fmaf(-(c1c2 * s3), (S0 * S1) * (C2 * S3), z);
        z = fmaf(-(s1 * c2 * c3), (S1 * S2) * C3, z);
        z = fmaf(-(s1 * s2 * s3), S0, z);
        lz[t] = z;
    }
    __syncthreads();

    // FC1: h[o] = relu(sum_j z[j]*W1[j,o] + b1[o]); 8 segments per output,
    // shuffle-reduced within each lane-octet (no extra barrier).
    if (t < 240) {
        const int o   = t >> 3;   // 0..29
        const int seg = t & 7;    // 0..7
        float acc = 0.f;
        #pragma unroll
        for (int i = 0; i < 25; ++i) {
            const int j = seg * 25 + i;
            if (j < 196) acc = fmaf(lz[j], W1[j * 30 + o], acc);
        }
        acc += __shfl_down(acc, 4, 8);
        acc += __shfl_down(acc, 2, 8);
        acc += __shfl_down(acc, 1, 8);
        if (seg == 0) lh[o] = fmaxf(acc + b1[o], 0.f);
    }
    __syncthreads();

    // FC2: out = h @ W2 + b2, W2 is (30,2) row-major.
    if (t < 2) {
        float acc = b2[t];
        #pragma unroll
        for (int k = 0; k < 30; ++k)
            acc = fmaf(lh[k], W2[k * 2 + t], acc);
        out[img * 2 + t] = acc;
    }
}

extern "C" void kernel_launch(void* const* d_in, const int* in_sizes, int n_in,
                              void* d_out, int out_size, void* d_ws, size_t ws_size,
                              hipStream_t stream) {
    const float* x  = (const float*)d_in[0];
    const float* qw = (const float*)d_in[1];
    const float* W1 = (const float*)d_in[2];
    const float* b1 = (const float*)d_in[3];
    const float* W2 = (const float*)d_in[4];
    const float* b2 = (const float*)d_in[5];
    float* out = (float*)d_out;

    const int B = in_sizes[0] / 784;   // 4096
    hipLaunchKernelGGL(hybrid_qnn_kernel, dim3(B), dim3(256), 0, stream,
                       x, qw, W1, b1, W2, b2, out);
}